// Round 8
// baseline (577.811 us; speedup 1.0000x reference)
//
#include <hip/hip_runtime.h>
#include <hip/hip_bf16.h>

typedef unsigned long long u64;

#define EPSV 1e-5

__device__ __forceinline__ int imax(int a, int b) { return a > b ? a : b; }

// ================= prep: pack binary weights (coalesced via LDS) + zero accs/halo region =================
struct PrepArgs {
    const float* src[10];  // conv1..7 (l=0..6), lin0..2 (l=7..9)
    u64* dst[10];          // conv: transposed [k*CW+w][Co]; lin: [o][8]
    int CW[10];
    int Co[10];
    int taps[10];          // 9 conv, 1 lin
    int rowbase[11];       // prefix over Co
    u64* zptr;             // accs (65536 words) + haloed act region (contiguous)
    int nzero;
};

__global__ __launch_bounds__(256) void prep_kernel(PrepArgs a) {
    __shared__ float buf[4608];  // max Ci*9 = 512*9
    const int blk = blockIdx.x;
    int z = blk * 256 + threadIdx.x;
    if (z < a.nzero) a.zptr[z] = 0ULL;

    int l = 0;
    while (l < 9 && blk >= a.rowbase[l + 1]) ++l;
    const int row = blk - a.rowbase[l];
    const int CW = a.CW[l];
    const int taps = a.taps[l];
    const int nf = CW * 64 * taps;
    const float* srow = a.src[l] + (size_t)row * nf;
    for (int i = threadIdx.x; i < nf; i += 256) buf[i] = srow[i];
    __syncthreads();
    const int t = threadIdx.x;
    if (t < taps * CW) {
        u64 bits = 0;
        if (taps == 9) {
            int k = t % 9, w = t / 9;
            for (int j = 0; j < 64; ++j) bits |= (u64)(buf[(w * 64 + j) * 9 + k] >= 0.f) << j;
            a.dst[l][(size_t)(k * CW + w) * a.Co[l] + row] = bits;
        } else {
            for (int j = 0; j < 64; ++j) bits |= (u64)(buf[t * 64 + j] >= 0.f) << j;
            a.dst[l][(size_t)row * CW + t] = bits;
        }
    }
}

// ================= conv0: lane=co, input band staged in LDS, fused sharded stats =================
__global__ __launch_bounds__(256) void conv0_lane(const float* __restrict__ x,
                                                  const float* __restrict__ wgt,
                                                  float* __restrict__ out,
                                                  double* __restrict__ dacc) {
    const int lane = threadIdx.x & 63;
    const int wave = threadIdx.x >> 6;
    float ws[27];
#pragma unroll
    for (int j = 0; j < 27; ++j) ws[j] = (wgt[lane * 27 + j] >= 0.f) ? 1.f : -1.f;

    const int gp0 = blockIdx.x * 32;
    const int n = gp0 >> 8;
    const int ypA = (gp0 >> 4) & 15;
    const int yb = 2 * ypA - 1;

    __shared__ float simg[3][6][34];
    const float* xb = x + (size_t)n * 3072;
    for (int t = threadIdx.x; t < 612; t += 256) {
        int ci = t / 204;
        int rem = t % 204;
        int r = rem / 34;
        int cc = rem % 34;
        int yy = yb + r;
        int xx = cc - 1;
        float v = 0.f;
        if ((unsigned)yy < 32u && (unsigned)xx < 32u) v = xb[(ci * 32 + yy) * 32 + xx];
        simg[ci][r][cc] = v;
    }
    __syncthreads();

    double s1 = 0.0, s2 = 0.0;
#pragma unroll 1
    for (int pi = 0; pi < 8; ++pi) {
        const int lp = wave * 8 + pi;
        const int gp = gp0 + lp;
        const int xp = lp & 15;
        const int rbase = 2 * (lp >> 4);
        const int cbase = 2 * xp;
        float win[3][4][4];
#pragma unroll
        for (int ci = 0; ci < 3; ++ci)
#pragma unroll
            for (int r = 0; r < 4; ++r)
#pragma unroll
                for (int c = 0; c < 4; ++c) win[ci][r][c] = simg[ci][rbase + r][cbase + c];
        float a00 = 0.f, a01 = 0.f, a10 = 0.f, a11 = 0.f;
#pragma unroll
        for (int ci = 0; ci < 3; ++ci)
#pragma unroll
            for (int ky = 0; ky < 3; ++ky)
#pragma unroll
                for (int kx = 0; kx < 3; ++kx) {
                    float wv = ws[ci * 9 + ky * 3 + kx];
                    a00 += win[ci][ky][kx] * wv;
                    a01 += win[ci][ky][kx + 1] * wv;
                    a10 += win[ci][ky + 1][kx] * wv;
                    a11 += win[ci][ky + 1][kx + 1] * wv;
                }
        float val = fmaxf(fmaxf(a00, a01), fmaxf(a10, a11));
        out[(size_t)gp * 64 + lane] = val;
        s1 += (double)val;
        s2 += (double)val * (double)val;
    }
    __shared__ double sh1[4][64], sh2[4][64];
    sh1[wave][lane] = s1;
    sh2[wave][lane] = s2;
    __syncthreads();
    if (threadIdx.x < 64) {
        double t1 = 0.0, t2 = 0.0;
#pragma unroll
        for (int r = 0; r < 4; ++r) { t1 += sh1[r][threadIdx.x]; t2 += sh2[r][threadIdx.x]; }
        double* sh = dacc + (size_t)(blockIdx.x & 7) * 1024;
        atomicAdd(&sh[2 * threadIdx.x], t1);
        atomicAdd(&sh[2 * threadIdx.x + 1], t2);
    }
}

// ================= bnpack float (layer 0) -> haloed act0 [n][18][18] =================
__global__ __launch_bounds__(256) void bnpack_f(const float* __restrict__ in,
                                                const double* __restrict__ dacc,
                                                const float* __restrict__ g,
                                                const float* __restrict__ b,
                                                u64* __restrict__ act, int count) {
    __shared__ float2 sthr[64];
    if (threadIdx.x < 64) {
        int i = threadIdx.x;
        double S1 = 0.0, S2 = 0.0;
#pragma unroll
        for (int s = 0; s < 8; ++s) {
            S1 += dacc[s * 1024 + 2 * i];
            S2 += dacc[s * 1024 + 2 * i + 1];
        }
        double m = S1 / count;
        double var = S2 / count - m * m;
        double sc = (double)g[i] / sqrt(var + EPSV);
        float2 r;
        if (sc == 0.0) r = make_float2(b[i] >= 0.f ? -3.0e38f : 3.0e38f, 1.f);
        else {
            double t = m - (double)b[i] / sc;
            r = make_float2((float)t, sc > 0.0 ? 1.f : -1.f);
        }
        sthr[i] = r;
    }
    __syncthreads();
    int idx = blockIdx.x * 256 + threadIdx.x;
    const float4* r4 = (const float4*)(in + (size_t)idx * 64);
    u64 bits = 0;
#pragma unroll
    for (int q = 0; q < 16; ++q) {
        float4 v = r4[q];
        float vv[4] = {v.x, v.y, v.z, v.w};
#pragma unroll
        for (int u = 0; u < 4; ++u) {
            int c = q * 4 + u;
            float2 t = sthr[c];
            bool bit = (t.y > 0.f) ? (vv[u] >= t.x) : (vv[u] <= t.x);
            bits |= (u64)bit << c;
        }
    }
    int n = idx >> 8, yp = (idx >> 4) & 15, xp = idx & 15;
    act[(size_t)(n * 18 + yp + 1) * 18 + xp + 1] = bits;
}

// ================= bnpack int16, coalesced reads, haloed or flat writes =================
// HALO=1: act [n][SH][SH][CW] halo-offset writes; HALO=0: act[tid] flat [pix][CW].
template <int HALO>
__global__ __launch_bounds__(256) void bnpack_i(const short* __restrict__ in,
                                                const u64* __restrict__ iacc,
                                                const float* __restrict__ g,
                                                const float* __restrict__ b,
                                                u64* __restrict__ act, int Co, int wshift,
                                                int hpshift, int SH, int count) {
    __shared__ int2 sthr[520];  // stride 65: breaks 8-way LDS bank conflict
    for (int i = threadIdx.x; i < Co; i += 256) {
        long long S1 = 0, S2 = 0;
#pragma unroll
        for (int s = 0; s < 8; ++s) {
            S1 += (long long)iacc[s * 1024 + 2 * i];
            S2 += (long long)iacc[s * 1024 + 2 * i + 1];
        }
        double m = (double)S1 / count;
        double var = (double)S2 / count - m * m;
        double sc = (double)g[i] / sqrt(var + EPSV);
        int2 r;
        if (sc == 0.0) r = make_int2(b[i] >= 0.f ? (int)0x80000000 : 0x7fffffff, 0);
        else {
            double t = m - (double)b[i] / sc;
            if (t > 1.0e9) t = 1.0e9;
            if (t < -1.0e9) t = -1.0e9;
            r = (sc > 0.0) ? make_int2((int)ceil(t), 0) : make_int2((int)floor(t), 1);
        }
        sthr[(i >> 6) * 65 + (i & 63)] = r;
    }
    __syncthreads();
    int tid = blockIdx.x * 256 + threadIdx.x;
    int w = tid & ((1 << wshift) - 1);
    int pix = tid >> wshift;
    const int4* r4 = (const int4*)(in + (size_t)pix * Co + (w << 6));
    u64 bits = 0;
#pragma unroll
    for (int q = 0; q < 8; ++q) {
        int4 v = r4[q];
        int words[4] = {v.x, v.y, v.z, v.w};
#pragma unroll
        for (int u = 0; u < 4; ++u) {
#pragma unroll
            for (int h = 0; h < 2; ++h) {
                int c = q * 8 + u * 2 + h;
                int val = (int)(short)((h == 0) ? (words[u] & 0xffff) : ((unsigned)words[u] >> 16));
                int2 t = sthr[w * 65 + c];
                bool bit = t.y ? (val <= t.x) : (val >= t.x);
                bits |= (u64)bit << c;
            }
        }
    }
    if (HALO) {
        int HP = 1 << hpshift;
        int n = pix >> (2 * hpshift);
        int p = pix & ((1 << (2 * hpshift)) - 1);
        int yp = p >> hpshift, xp = p & (HP - 1);
        act[((size_t)((n * SH + yp + 1) * SH + xp + 1) << wshift) + w] = bits;
    } else {
        act[tid] = bits;
    }
}

// ================= binary conv lane=co, haloed input (layers 1..4) =================
// in: u64 [n][(HIN+2)^2][CW], halo words ZERO. No clamp/cndmask: halo taps contribute
// C[k]=sum_w(64-2popc(wgt)) which border pixels subtract (interior: none).
// Fully unrolled (compile-time indices -> VGPR residency; dynamic index => scratch).
// WC: words loaded per position chunk (ulonglong2 when 2).
template <int CW, int HIN, bool POOL, int PPW, int WC>
__global__ __launch_bounds__(256) void bconv_lane(const u64* __restrict__ in,
                                                  const u64* __restrict__ wpkT,
                                                  short* __restrict__ out,
                                                  u64* __restrict__ iacc, int Co) {
    constexpr int H2 = HIN + 2;
    constexpr int HP = POOL ? HIN / 2 : HIN;
    constexpr int NPP = HP * HP;
    constexpr int WS = POOL ? 4 : 3;
    constexpr int NA = POOL ? 4 : 1;
    const int lane = threadIdx.x & 63;
    const int wave = threadIdx.x >> 6;
    const int co = blockIdx.y * 64 + lane;

    u64 wgt[9 * CW];
#pragma unroll
    for (int j = 0; j < 9 * CW; ++j) wgt[j] = wpkT[(size_t)j * Co + co];
    int C[9];
#pragma unroll
    for (int k = 0; k < 9; ++k) {
        int s = 0;
#pragma unroll
        for (int w = 0; w < CW; ++w) s += 64 - 2 * (int)__popcll(wgt[k * CW + w]);
        C[k] = s;
    }

    int s1 = 0;
    long long s2 = 0;
    const int gp0 = (blockIdx.x * 4 + wave) * PPW;
#pragma unroll
    for (int pi = 0; pi < PPW; ++pi) {
        const int gp = gp0 + pi;
        const int n = gp / NPP;
        const int pp = gp % NPP;
        const int yp = pp / HP, xp = pp % HP;
        const int yb = POOL ? 2 * yp : yp;  // halo coord of window top
        const int xb = POOL ? 2 * xp : xp;
        const u64* inb = in + (size_t)n * (H2 * H2 * CW);

        int acc[NA];
#pragma unroll
        for (int i = 0; i < NA; ++i) acc[i] = 0;

#pragma unroll
        for (int w0 = 0; w0 < CW; w0 += WC) {
            u64 win[WS][WS][WC];
#pragma unroll
            for (int r = 0; r < WS; ++r)
#pragma unroll
                for (int c = 0; c < WS; ++c) {
                    const u64* p = inb + ((size_t)(yb + r) * H2 + (xb + c)) * CW + w0;
                    if (WC == 1) {
                        win[r][c][0] = p[0];
                    } else {
                        ulonglong2 v = *(const ulonglong2*)p;
                        win[r][c][0] = v.x;
                        win[r][c][1] = v.y;
                    }
                }
#pragma unroll
            for (int w = 0; w < WC; ++w) {
                if constexpr (POOL) {
#pragma unroll
                    for (int py = 0; py < 2; ++py)
#pragma unroll
                        for (int px = 0; px < 2; ++px)
#pragma unroll
                            for (int ky = 0; ky < 3; ++ky)
#pragma unroll
                                for (int kx = 0; kx < 3; ++kx)
                                    acc[py * 2 + px] +=
                                        64 - 2 * (int)__popcll(win[py + ky][px + kx][w] ^
                                                               wgt[(ky * 3 + kx) * CW + w0 + w]);
                } else {
#pragma unroll
                    for (int ky = 0; ky < 3; ++ky)
#pragma unroll
                        for (int kx = 0; kx < 3; ++kx)
                            acc[0] += 64 - 2 * (int)__popcll(win[ky][kx][w] ^
                                                             wgt[(ky * 3 + kx) * CW + w0 + w]);
                }
            }
        }

        // border correction (wave-uniform branch; interior pixels skip entirely)
        const bool interior = POOL ? (yp > 0 && yp < HP - 1 && xp > 0 && xp < HP - 1)
                                   : (yp > 0 && yp < HIN - 1 && xp > 0 && xp < HIN - 1);
        int v[NA];
        if (interior) {
#pragma unroll
            for (int i = 0; i < NA; ++i) v[i] = acc[i];
        } else {
            bool rp[WS], cp[WS];
#pragma unroll
            for (int r = 0; r < WS; ++r) rp[r] = ((unsigned)(yb + r - 1) >= (unsigned)HIN);
#pragma unroll
            for (int c = 0; c < WS; ++c) cp[c] = ((unsigned)(xb + c - 1) >= (unsigned)HIN);
            if constexpr (POOL) {
#pragma unroll
                for (int py = 0; py < 2; ++py)
#pragma unroll
                    for (int px = 0; px < 2; ++px) {
                        int corr = 0;
#pragma unroll
                        for (int ky = 0; ky < 3; ++ky)
#pragma unroll
                            for (int kx = 0; kx < 3; ++kx)
                                if (rp[py + ky] || cp[px + kx]) corr += C[ky * 3 + kx];
                        v[py * 2 + px] = acc[py * 2 + px] - corr;
                    }
            } else {
                int corr = 0;
#pragma unroll
                for (int ky = 0; ky < 3; ++ky)
#pragma unroll
                    for (int kx = 0; kx < 3; ++kx)
                        if (rp[ky] || cp[kx]) corr += C[ky * 3 + kx];
                v[0] = acc[0] - corr;
            }
        }
        int ival;
        if constexpr (POOL)
            ival = imax(imax(v[0], v[1]), imax(v[2], v[3]));
        else
            ival = v[0];
        out[(size_t)gp * Co + co] = (short)ival;
        s1 += ival;
        s2 += (long long)ival * ival;
    }

    __shared__ u64 sacc[128];
    if (threadIdx.x < 128) sacc[threadIdx.x] = 0ULL;
    __syncthreads();
    atomicAdd(&sacc[lane], (u64)(long long)s1);
    atomicAdd(&sacc[64 + lane], (u64)s2);
    __syncthreads();
    u64* sh = iacc + (size_t)(blockIdx.x & 7) * 1024;
    if (threadIdx.x < 64)
        atomicAdd(&sh[2 * (blockIdx.y * 64 + threadIdx.x)], sacc[threadIdx.x]);
    else if (threadIdx.x < 128)
        atomicAdd(&sh[2 * (blockIdx.y * 64 + threadIdx.x - 64) + 1], sacc[threadIdx.x]);
}

// ================= binary conv for tiny images (layers 5..7, flat layout) =================
template <int CW, int HIN, bool POOL>
__global__ __launch_bounds__(256) void bconv_tiny(const u64* __restrict__ in,
                                                  const u64* __restrict__ wpkT,
                                                  short* __restrict__ out,
                                                  u64* __restrict__ iacc, int Co) {
    constexpr int NPX = HIN * HIN;
    constexpr int HP = POOL ? HIN / 2 : HIN;
    const int lane = threadIdx.x & 63;
    const int co = blockIdx.y * 64 + lane;
    const int n = blockIdx.x * 4 + (threadIdx.x >> 6);
    const u64* inb = in + (size_t)n * CW * NPX;
    int acc[NPX];
#pragma unroll
    for (int i = 0; i < NPX; ++i) acc[i] = 0;

#pragma unroll 1
    for (int w = 0; w < CW; ++w) {
        u64 win[NPX];
#pragma unroll
        for (int i = 0; i < NPX; ++i) win[i] = inb[i * CW + w];
#pragma unroll
        for (int k = 0; k < 9; ++k) {
            u64 wb = wpkT[(size_t)(k * CW + w) * Co + co];
            const int ky = k / 3, kx = k % 3;
#pragma unroll
            for (int py = 0; py < HIN; ++py)
#pragma unroll
                for (int px = 0; px < HIN; ++px) {
                    const int yy = py + ky - 1, xx = px + kx - 1;
                    if (yy >= 0 && yy < HIN && xx >= 0 && xx < HIN)
                        acc[py * HIN + px] += 64 - 2 * (int)__popcll(win[yy * HIN + xx] ^ wb);
                }
        }
    }

    short vals[HP * HP];
    if constexpr (POOL) {
#pragma unroll
        for (int py = 0; py < HP; ++py)
#pragma unroll
            for (int px = 0; px < HP; ++px)
                vals[py * HP + px] = (short)imax(
                    imax(acc[(2 * py) * HIN + 2 * px], acc[(2 * py) * HIN + 2 * px + 1]),
                    imax(acc[(2 * py + 1) * HIN + 2 * px], acc[(2 * py + 1) * HIN + 2 * px + 1]));
    } else {
#pragma unroll
        for (int i = 0; i < NPX; ++i) vals[i] = (short)acc[i];
    }
#pragma unroll
    for (int p = 0; p < HP * HP; ++p) out[(size_t)(n * HP * HP + p) * Co + co] = vals[p];

    long long s1 = 0, s2 = 0;
#pragma unroll
    for (int p = 0; p < HP * HP; ++p) {
        s1 += vals[p];
        s2 += (long long)vals[p] * vals[p];
    }
    __shared__ u64 sacc[128];
    if (threadIdx.x < 128) sacc[threadIdx.x] = 0ULL;
    __syncthreads();
    atomicAdd(&sacc[lane], (u64)s1);
    atomicAdd(&sacc[64 + lane], (u64)s2);
    __syncthreads();
    u64* sh = iacc + (size_t)(blockIdx.x & 7) * 1024;
    if (threadIdx.x < 64)
        atomicAdd(&sh[2 * (blockIdx.y * 64 + threadIdx.x)], sacc[threadIdx.x]);
    else if (threadIdx.x < 128)
        atomicAdd(&sh[2 * (blockIdx.y * 64 + threadIdx.x - 64) + 1], sacc[threadIdx.x]);
}

// ================= binarized linear + BN1 (+ hardtanh) =================
__global__ __launch_bounds__(256) void lin_kernel(const u64* __restrict__ hp,
                                                  const u64* __restrict__ wp,
                                                  const float* __restrict__ lb,
                                                  const float* __restrict__ g,
                                                  const float* __restrict__ bta,
                                                  float* __restrict__ z, int O, int applyHt) {
    int o = blockIdx.x;
    int n = threadIdx.x;
    const u64* hr = hp + n * 8;
    const u64* wr = wp + o * 8;
    int s = 0;
#pragma unroll
    for (int w = 0; w < 8; ++w) s += (int)__popcll(hr[w] ^ wr[w]);
    float val = (float)(512 - 2 * s) + lb[o];
    __shared__ double sh1[256], sh2[256];
    sh1[n] = (double)val;
    sh2[n] = (double)val * (double)val;
    __syncthreads();
    for (int st = 128; st > 0; st >>= 1) {
        if (n < st) {
            sh1[n] += sh1[n + st];
            sh2[n] += sh2[n + st];
        }
        __syncthreads();
    }
    __shared__ float sm, siv;
    if (n == 0) {
        double m = sh1[0] / 256.0;
        double var = sh2[0] / 256.0 - m * m;
        sm = (float)m;
        siv = (float)(1.0 / sqrt(var + EPSV));
    }
    __syncthreads();
    float zz = g[o] * (val - sm) * siv + bta[o];
    if (applyHt) zz = fminf(1.f, fmaxf(-1.f, zz));
    z[(size_t)n * O + o] = zz;
}

__global__ void pack_rows(const float* __restrict__ z, u64* __restrict__ hp) {
    int idx = blockIdx.x * 256 + threadIdx.x;
    if (idx >= 2048) return;
    int ww = idx & 7;
    int n = idx >> 3;
    u64 bits = 0;
    const float* row = z + (size_t)n * 512 + (ww << 6);
    for (int j = 0; j < 64; ++j) bits |= (u64)(row[j] >= 0.f) << j;
    hp[idx] = bits;
}

__global__ void lsm_kernel(const float* __restrict__ z, float* __restrict__ out) {
    int n = blockIdx.x * 64 + threadIdx.x;
    if (n >= 256) return;
    float v[10];
    float m = -1e30f;
#pragma unroll
    for (int i = 0; i < 10; ++i) {
        v[i] = z[n * 10 + i];
        m = fmaxf(m, v[i]);
    }
    float s = 0.f;
#pragma unroll
    for (int i = 0; i < 10; ++i) s += expf(v[i] - m);
    float ls = logf(s);
#pragma unroll
    for (int i = 0; i < 10; ++i) out[n * 10 + i] = v[i] - m - ls;
}

extern "C" void kernel_launch(void* const* d_in, const int* in_sizes, int n_in, void* d_out,
                              int out_size, void* d_ws, size_t ws_size, hipStream_t stream) {
    (void)in_sizes; (void)n_in; (void)out_size; (void)ws_size;
    const float* x = (const float*)d_in[0];
    const float *cw[8], *cb[8], *cg[8], *ct[8];
    for (int i = 0; i < 8; ++i) {
        cw[i] = (const float*)d_in[1 + 4 * i];
        cb[i] = (const float*)d_in[2 + 4 * i];
        cg[i] = (const float*)d_in[3 + 4 * i];
        ct[i] = (const float*)d_in[4 + 4 * i];
    }
    const float *lw[3], *lb[3], *lg[3], *lt[3];
    for (int i = 0; i < 3; ++i) {
        lw[i] = (const float*)d_in[33 + 4 * i];
        lb[i] = (const float*)d_in[34 + 4 * i];
        lg[i] = (const float*)d_in[35 + 4 * i];
        lt[i] = (const float*)d_in[36 + 4 * i];
    }

    static const int CIs[8] = {3, 64, 128, 256, 256, 512, 512, 512};
    static const int COs[8] = {64, 128, 256, 256, 512, 512, 512, 512};

    char* ws = (char*)d_ws;
    size_t off = 0;
    auto alloc = [&](size_t bytes) -> void* {
        void* p = ws + off;
        off += (bytes + 255) & ~(size_t)255;
        return p;
    };

    u64* wpkT[8] = {};
    for (int i = 1; i < 8; ++i) wpkT[i] = (u64*)alloc((size_t)COs[i] * 9 * (CIs[i] / 64) * 8);
    u64* wpl[3];
    int LO[3] = {512, 512, 10};
    for (int i = 0; i < 3; ++i) wpl[i] = (u64*)alloc((size_t)LO[i] * 8 * 8);

    // sharded stats (zeroed by prep): 8 layers x 8 shards x 1024 u64 — MUST be
    // immediately followed by the haloed act region (single zero span in prep).
    u64* accs = (u64*)alloc((size_t)8 * 8 * 1024 * 8);  // 524288 B, 256-aligned
    // haloed acts (inputs to L1..L4), contiguous with accs:
    // act0 [256][18][18] (82944 w), act1 [256][10][10][2] (51200),
    // act2 [256][10][10][4] (102400), act3 [256][6][6][4] (36864)
    u64* actH = (u64*)alloc((size_t)273408 * 8);
    u64* act0 = actH;
    u64* act1 = actH + 82944;
    u64* act2 = actH + 134144;
    u64* act3 = actH + 236544;
    // flat acts (inputs to tiny layers + FC)
    u64* act4 = (u64*)alloc((size_t)256 * 16 * 8 * 8);
    u64* act5 = (u64*)alloc((size_t)256 * 4 * 8 * 8);
    u64* act6 = (u64*)alloc((size_t)256 * 4 * 8 * 8);
    u64* act7 = (u64*)alloc((size_t)256 * 1 * 8 * 8);
    u64* fcs0 = (u64*)alloc(2048 * 8);
    u64* fcs1 = (u64*)alloc(2048 * 8);
    float* out0 = (float*)alloc((size_t)65536 * 64 * 4);
    short* i16A = (short*)alloc((size_t)16384 * 256 * 2);
    short* i16B = (short*)alloc((size_t)16384 * 256 * 2);
    float* z0 = (float*)alloc((size_t)256 * 512 * 4);
    float* z1 = (float*)alloc((size_t)256 * 512 * 4);
    float* z2 = (float*)alloc((size_t)256 * 10 * 4);
    double* dacc0 = (double*)accs;
    auto iacc = [&](int layer) { return accs + (size_t)layer * 8192; };

    // ---- prep ----
    PrepArgs pa;
    int rb = 0;
    for (int i = 1; i < 8; ++i) {
        int e = i - 1;
        pa.src[e] = cw[i];
        pa.dst[e] = wpkT[i];
        pa.CW[e] = CIs[i] / 64;
        pa.Co[e] = COs[i];
        pa.taps[e] = 9;
        pa.rowbase[e] = rb;
        rb += COs[i];
    }
    for (int i = 0; i < 3; ++i) {
        int e = 7 + i;
        pa.src[e] = lw[i];
        pa.dst[e] = wpl[i];
        pa.CW[e] = 8;
        pa.Co[e] = LO[i];
        pa.taps[e] = 1;
        pa.rowbase[e] = rb;
        rb += LO[i];
    }
    pa.rowbase[10] = rb;  // 3722 blocks; 3722*256 = 952832 >= nzero
    pa.zptr = accs;
    pa.nzero = 65536 + 273408;
    prep_kernel<<<rb, 256, 0, stream>>>(pa);

    // ---- L0 ----
    conv0_lane<<<2048, 256, 0, stream>>>(x, cw[0], out0, dacc0);
    bnpack_f<<<256, 256, 0, stream>>>(out0, dacc0, cg[0], ct[0], act0, 65536);

    // ---- L1: 64ch 16x16 -> 128ch, pool -> 8x8 ----
    bconv_lane<1, 16, true, 2, 1><<<dim3(2048, 2), 256, 0, stream>>>(act0, wpkT[1], i16A, iacc(1), 128);
    bnpack_i<1><<<128, 256, 0, stream>>>(i16A, iacc(1), cg[1], ct[1], act1, 128, 1, 3, 10, 16384);

    // ---- L2: 128ch 8x8 -> 256ch ----
    bconv_lane<2, 8, false, 2, 2><<<dim3(2048, 4), 256, 0, stream>>>(act1, wpkT[2], i16B, iacc(2), 256);
    bnpack_i<1><<<256, 256, 0, stream>>>(i16B, iacc(2), cg[2], ct[2], act2, 256, 2, 3, 10, 16384);

    // ---- L3: 256ch 8x8 -> 256ch, pool -> 4x4 ----
    bconv_lane<4, 8, true, 1, 2><<<dim3(1024, 4), 256, 0, stream>>>(act2, wpkT[3], i16A, iacc(3), 256);
    bnpack_i<1><<<64, 256, 0, stream>>>(i16A, iacc(3), cg[3], ct[3], act3, 256, 2, 2, 6, 4096);

    // ---- L4: 256ch 4x4 -> 512ch (output flat for tiny layers) ----
    bconv_lane<4, 4, false, 1, 2><<<dim3(1024, 8), 256, 0, stream>>>(act3, wpkT[4], i16B, iacc(4), 512);
    bnpack_i<0><<<128, 256, 0, stream>>>(i16B, iacc(4), cg[4], ct[4], act4, 512, 3, 2, 0, 4096);

    // ---- L5: 512ch 4x4 -> 512ch, pool -> 2x2 (tiny) ----
    bconv_tiny<8, 4, true><<<dim3(64, 8), 256, 0, stream>>>(act4, wpkT[5], i16A, iacc(5), 512);
    bnpack_i<0><<<32, 256, 0, stream>>>(i16A, iacc(5), cg[5], ct[5], act5, 512, 3, 1, 0, 1024);

    // ---- L6: 512ch 2x2 -> 512ch (tiny) ----
    bconv_tiny<8, 2, false><<<dim3(64, 8), 256, 0, stream>>>(act5, wpkT[6], i16B, iacc(6), 512);
    bnpack_i<0><<<32, 256, 0, stream>>>(i16B, iacc(6), cg[6], ct[6], act6, 512, 3, 1, 0, 1024);

    // ---- L7: 512ch 2x2 -> 512ch, pool -> 1x1 (tiny) ----
    bconv_tiny<8, 2, true><<<dim3(64, 8), 256, 0, stream>>>(act6, wpkT[7], i16A, iacc(7), 512);
    bnpack_i<0><<<8, 256, 0, stream>>>(i16A, iacc(7), cg[7], ct[7], act7, 512, 3, 0, 0, 256);

    // ---- FC ----
    lin_kernel<<<512, 256, 0, stream>>>(act7, wpl[0], lb[0], lg[0], lt[0], z0, 512, 1);
    pack_rows<<<8, 256, 0, stream>>>(z0, fcs0);
    lin_kernel<<<512, 256, 0, stream>>>(fcs0, wpl[1], lb[1], lg[1], lt[1], z1, 512, 1);
    pack_rows<<<8, 256, 0, stream>>>(z1, fcs1);
    lin_kernel<<<10, 256, 0, stream>>>(fcs1, wpl[2], lb[2], lg[2], lt[2], z2, 10, 0);
    lsm_kernel<<<4, 64, 0, stream>>>(z2, (float*)d_out);
}

// Round 9
// 403.992 us; speedup vs baseline: 1.4303x; 1.4303x over previous
//
#include <hip/hip_runtime.h>
#include <hip/hip_bf16.h>

typedef unsigned long long u64;

#define EPSV 1e-5

__device__ __forceinline__ int imax(int a, int b) { return a > b ? a : b; }
__device__ __forceinline__ int iclamp(int v, int lo, int hi) { return v < lo ? lo : (v > hi ? hi : v); }

// ================= prep: pack binary weights (coalesced via LDS) + zero stats shards =================
struct PrepArgs {
    const float* src[10];  // conv1..7 (l=0..6), lin0..2 (l=7..9)
    u64* dst[10];          // conv: transposed [k*CW+w][Co]; lin: [o][8]
    int CW[10];
    int Co[10];
    int taps[10];          // 9 conv, 1 lin
    int rowbase[11];       // prefix over Co
    u64* accs;
    int naccs;
};

__global__ __launch_bounds__(256) void prep_kernel(PrepArgs a) {
    __shared__ float buf[4608];  // max Ci*9 = 512*9
    const int blk = blockIdx.x;
    int z = blk * 18 + threadIdx.x;
    if (threadIdx.x < 18 && z < a.naccs) a.accs[z] = 0ULL;

    int l = 0;
    while (l < 9 && blk >= a.rowbase[l + 1]) ++l;
    const int row = blk - a.rowbase[l];
    const int CW = a.CW[l];
    const int taps = a.taps[l];
    const int nf = CW * 64 * taps;
    const float* srow = a.src[l] + (size_t)row * nf;
    for (int i = threadIdx.x; i < nf; i += 256) buf[i] = srow[i];
    __syncthreads();
    const int t = threadIdx.x;
    if (t < taps * CW) {
        u64 bits = 0;
        if (taps == 9) {
            int k = t % 9, w = t / 9;
            for (int j = 0; j < 64; ++j) bits |= (u64)(buf[(w * 64 + j) * 9 + k] >= 0.f) << j;
            a.dst[l][(size_t)(k * CW + w) * a.Co[l] + row] = bits;
        } else {
            for (int j = 0; j < 64; ++j) bits |= (u64)(buf[t * 64 + j] >= 0.f) << j;
            a.dst[l][(size_t)row * CW + t] = bits;
        }
    }
}

// ================= conv0: lane=co, input band staged in LDS, fused sharded stats =================
__global__ __launch_bounds__(256) void conv0_lane(const float* __restrict__ x,
                                                  const float* __restrict__ wgt,
                                                  float* __restrict__ out,
                                                  double* __restrict__ dacc) {
    const int lane = threadIdx.x & 63;
    const int wave = threadIdx.x >> 6;
    float ws[27];
#pragma unroll
    for (int j = 0; j < 27; ++j) ws[j] = (wgt[lane * 27 + j] >= 0.f) ? 1.f : -1.f;

    const int gp0 = blockIdx.x * 32;
    const int n = gp0 >> 8;
    const int ypA = (gp0 >> 4) & 15;
    const int yb = 2 * ypA - 1;

    __shared__ float simg[3][6][34];
    const float* xb = x + (size_t)n * 3072;
    for (int t = threadIdx.x; t < 612; t += 256) {
        int ci = t / 204;
        int rem = t % 204;
        int r = rem / 34;
        int cc = rem % 34;
        int yy = yb + r;
        int xx = cc - 1;
        float v = 0.f;
        if ((unsigned)yy < 32u && (unsigned)xx < 32u) v = xb[(ci * 32 + yy) * 32 + xx];
        simg[ci][r][cc] = v;
    }
    __syncthreads();

    double s1 = 0.0, s2 = 0.0;
#pragma unroll 1
    for (int pi = 0; pi < 8; ++pi) {
        const int lp = wave * 8 + pi;
        const int gp = gp0 + lp;
        const int xp = lp & 15;
        const int rbase = 2 * (lp >> 4);
        const int cbase = 2 * xp;
        float win[3][4][4];
#pragma unroll
        for (int ci = 0; ci < 3; ++ci)
#pragma unroll
            for (int r = 0; r < 4; ++r)
#pragma unroll
                for (int c = 0; c < 4; ++c) win[ci][r][c] = simg[ci][rbase + r][cbase + c];
        float a00 = 0.f, a01 = 0.f, a10 = 0.f, a11 = 0.f;
#pragma unroll
        for (int ci = 0; ci < 3; ++ci)
#pragma unroll
            for (int ky = 0; ky < 3; ++ky)
#pragma unroll
                for (int kx = 0; kx < 3; ++kx) {
                    float wv = ws[ci * 9 + ky * 3 + kx];
                    a00 += win[ci][ky][kx] * wv;
                    a01 += win[ci][ky][kx + 1] * wv;
                    a10 += win[ci][ky + 1][kx] * wv;
                    a11 += win[ci][ky + 1][kx + 1] * wv;
                }
        float val = fmaxf(fmaxf(a00, a01), fmaxf(a10, a11));
        out[(size_t)gp * 64 + lane] = val;
        s1 += (double)val;
        s2 += (double)val * (double)val;
    }
    __shared__ double sh1[4][64], sh2[4][64];
    sh1[wave][lane] = s1;
    sh2[wave][lane] = s2;
    __syncthreads();
    if (threadIdx.x < 64) {
        double t1 = 0.0, t2 = 0.0;
#pragma unroll
        for (int r = 0; r < 4; ++r) { t1 += sh1[r][threadIdx.x]; t2 += sh2[r][threadIdx.x]; }
        double* sh = dacc + (size_t)(blockIdx.x & 7) * 1024;
        atomicAdd(&sh[2 * threadIdx.x], t1);
        atomicAdd(&sh[2 * threadIdx.x + 1], t2);
    }
}

// ================= bnpack float (layer 0), fused thresholds from 8 shards =================
__global__ __launch_bounds__(256) void bnpack_f(const float* __restrict__ in,
                                                const double* __restrict__ dacc,
                                                const float* __restrict__ g,
                                                const float* __restrict__ b,
                                                u64* __restrict__ act, int count) {
    __shared__ float2 sthr[64];
    if (threadIdx.x < 64) {
        int i = threadIdx.x;
        double S1 = 0.0, S2 = 0.0;
#pragma unroll
        for (int s = 0; s < 8; ++s) {
            S1 += dacc[s * 1024 + 2 * i];
            S2 += dacc[s * 1024 + 2 * i + 1];
        }
        double m = S1 / count;
        double var = S2 / count - m * m;
        double sc = (double)g[i] / sqrt(var + EPSV);
        float2 r;
        if (sc == 0.0) r = make_float2(b[i] >= 0.f ? -3.0e38f : 3.0e38f, 1.f);
        else {
            double t = m - (double)b[i] / sc;
            r = make_float2((float)t, sc > 0.0 ? 1.f : -1.f);
        }
        sthr[i] = r;
    }
    __syncthreads();
    int idx = blockIdx.x * 256 + threadIdx.x;
    const float4* r4 = (const float4*)(in + (size_t)idx * 64);
    u64 bits = 0;
#pragma unroll
    for (int q = 0; q < 16; ++q) {
        float4 v = r4[q];
        float vv[4] = {v.x, v.y, v.z, v.w};
#pragma unroll
        for (int u = 0; u < 4; ++u) {
            int c = q * 4 + u;
            float2 t = sthr[c];
            bool bit = (t.y > 0.f) ? (vv[u] >= t.x) : (vv[u] <= t.x);
            bits |= (u64)bit << c;
        }
    }
    act[idx] = bits;
}

// ================= bnpack int16, coalesced, padded threshold table (stride 65) =================
__global__ __launch_bounds__(256) void bnpack_i(const short* __restrict__ in,
                                                const u64* __restrict__ iacc,
                                                const float* __restrict__ g,
                                                const float* __restrict__ b,
                                                u64* __restrict__ act, int Co, int wshift,
                                                int count) {
    __shared__ int2 sthr[520];  // 8*65
    for (int i = threadIdx.x; i < Co; i += 256) {
        long long S1 = 0, S2 = 0;
#pragma unroll
        for (int s = 0; s < 8; ++s) {
            S1 += (long long)iacc[s * 1024 + 2 * i];
            S2 += (long long)iacc[s * 1024 + 2 * i + 1];
        }
        double m = (double)S1 / count;
        double var = (double)S2 / count - m * m;
        double sc = (double)g[i] / sqrt(var + EPSV);
        int2 r;
        if (sc == 0.0) r = make_int2(b[i] >= 0.f ? (int)0x80000000 : 0x7fffffff, 0);
        else {
            double t = m - (double)b[i] / sc;
            if (t > 1.0e9) t = 1.0e9;
            if (t < -1.0e9) t = -1.0e9;
            r = (sc > 0.0) ? make_int2((int)ceil(t), 0) : make_int2((int)floor(t), 1);
        }
        sthr[(i >> 6) * 65 + (i & 63)] = r;
    }
    __syncthreads();
    int tid = blockIdx.x * 256 + threadIdx.x;
    int w = tid & ((1 << wshift) - 1);
    int pix = tid >> wshift;
    const int4* r4 = (const int4*)(in + (size_t)pix * Co + (w << 6));
    u64 bits = 0;
#pragma unroll
    for (int q = 0; q < 8; ++q) {
        int4 v = r4[q];
        int words[4] = {v.x, v.y, v.z, v.w};
#pragma unroll
        for (int u = 0; u < 4; ++u) {
#pragma unroll
            for (int h = 0; h < 2; ++h) {
                int c = q * 8 + u * 2 + h;
                int val = (int)(short)((h == 0) ? (words[u] & 0xffff) : ((unsigned)words[u] >> 16));
                int2 t = sthr[w * 65 + c];
                bool bit = t.y ? (val <= t.x) : (val >= t.x);
                bits |= (u64)bit << c;
            }
        }
    }
    act[tid] = bits;
}

// ================= row-sliding binary conv, lane=co (layers 1..4) =================
// Wave = one output row (HP px); weights amortized over the row; sliding window
// registers (2 new cols/px pool, 1 col/px non-pool). All array indices are
// compile-time literals after unrolling (dynamic index => scratch spill, round-4).
// INTERIOR: all window rows valid -> no per-tap selects (wave-uniform split).
template <int CW, int HIN, bool POOL, int WC, bool INTERIOR>
__device__ __forceinline__ void row_accum(const u64* __restrict__ inb,
                                          const u64* __restrict__ wpkT, int Co, int co,
                                          const int* yoff, const bool* ry, int* acc) {
    constexpr int HP = POOL ? HIN / 2 : HIN;
    constexpr int WS = POOL ? 4 : 3;
    constexpr int NA = POOL ? 4 : 1;
#pragma unroll 1
    for (int w0 = 0; w0 < CW; w0 += WC) {
        u64 wg[9 * WC];
#pragma unroll
        for (int k = 0; k < 9; ++k)
#pragma unroll
            for (int w = 0; w < WC; ++w)
                wg[k * WC + w] = wpkT[(size_t)(k * CW + w0 + w) * Co + co];
        u64 cur[WS][WS][WC];
#pragma unroll
        for (int d = 0; d < WS; ++d) {
            int cc = d - 1;
            int ccc = cc < 0 ? 0 : cc;
#pragma unroll
            for (int r = 0; r < WS; ++r) {
                const u64* p = inb + yoff[r] + ccc * CW + w0;
                if (WC == 1) {
                    cur[r][d][0] = p[0];
                } else {
                    ulonglong2 v = *(const ulonglong2*)p;
                    cur[r][d][0] = v.x;
                    cur[r][d][1] = v.y;
                }
            }
        }
#pragma unroll
        for (int xp = 0; xp < HP; ++xp) {
            if constexpr (POOL) {
#pragma unroll
                for (int py = 0; py < 2; ++py)
#pragma unroll
                    for (int qx = 0; qx < 2; ++qx)
#pragma unroll
                        for (int ky = 0; ky < 3; ++ky)
#pragma unroll
                            for (int kx = 0; kx < 3; ++kx) {
                                int d = qx + kx;
                                int cc = 2 * xp + d - 1;
                                if (cc >= 0 && cc < HIN) {  // folds (xp,d literal)
#pragma unroll
                                    for (int w = 0; w < WC; ++w) {
                                        int pcv = 64 - 2 * (int)__popcll(cur[py + ky][d][w] ^
                                                                         wg[(ky * 3 + kx) * WC + w]);
                                        if constexpr (INTERIOR)
                                            acc[xp * NA + py * 2 + qx] += pcv;
                                        else
                                            acc[xp * NA + py * 2 + qx] += ry[py + ky] ? pcv : 0;
                                    }
                                }
                            }
            } else {
#pragma unroll
                for (int ky = 0; ky < 3; ++ky)
#pragma unroll
                    for (int kx = 0; kx < 3; ++kx) {
                        int cc = xp + kx - 1;
                        if (cc >= 0 && cc < HIN) {
#pragma unroll
                            for (int w = 0; w < WC; ++w) {
                                int pcv = 64 - 2 * (int)__popcll(cur[ky][kx][w] ^
                                                                 wg[(ky * 3 + kx) * WC + w]);
                                if constexpr (INTERIOR)
                                    acc[xp] += pcv;
                                else
                                    acc[xp] += ry[ky] ? pcv : 0;
                            }
                        }
                    }
            }
            if (xp < HP - 1) {
                if constexpr (POOL) {
#pragma unroll
                    for (int r = 0; r < WS; ++r)
#pragma unroll
                        for (int w = 0; w < WC; ++w) {
                            cur[r][0][w] = cur[r][2][w];
                            cur[r][1][w] = cur[r][3][w];
                        }
#pragma unroll
                    for (int dd = 2; dd < 4; ++dd) {
                        int cc = 2 * (xp + 1) + dd - 1;
                        int ccc = cc >= HIN ? HIN - 1 : cc;
#pragma unroll
                        for (int r = 0; r < WS; ++r) {
                            const u64* p = inb + yoff[r] + ccc * CW + w0;
                            if (WC == 1) {
                                cur[r][dd][0] = p[0];
                            } else {
                                ulonglong2 v = *(const ulonglong2*)p;
                                cur[r][dd][0] = v.x;
                                cur[r][dd][1] = v.y;
                            }
                        }
                    }
                } else {
#pragma unroll
                    for (int r = 0; r < WS; ++r)
#pragma unroll
                        for (int w = 0; w < WC; ++w) {
                            cur[r][0][w] = cur[r][1][w];
                            cur[r][1][w] = cur[r][2][w];
                        }
                    int cc = xp + 2;
                    int ccc = cc >= HIN ? HIN - 1 : cc;
#pragma unroll
                    for (int r = 0; r < WS; ++r) {
                        const u64* p = inb + yoff[r] + ccc * CW + w0;
                        if (WC == 1) {
                            cur[r][2][0] = p[0];
                        } else {
                            ulonglong2 v = *(const ulonglong2*)p;
                            cur[r][2][0] = v.x;
                            cur[r][2][1] = v.y;
                        }
                    }
                }
            }
        }
    }
}

template <int CW, int HIN, bool POOL, int WC>
__global__ __launch_bounds__(256) void bconv_row(const u64* __restrict__ in,
                                                 const u64* __restrict__ wpkT,
                                                 short* __restrict__ out,
                                                 u64* __restrict__ iacc, int Co) {
    constexpr int HP = POOL ? HIN / 2 : HIN;
    constexpr int WS = POOL ? 4 : 3;
    constexpr int NA = POOL ? 4 : 1;
    const int lane = threadIdx.x & 63;
    const int co = blockIdx.y * 64 + lane;
    const int grow = blockIdx.x * 4 + (threadIdx.x >> 6);  // n*HP + yp
    const int n = grow / HP;
    const int yp = grow % HP;
    const int y0 = (POOL ? 2 * yp : yp) - 1;
    const u64* inb = in + (size_t)n * (HIN * HIN * CW);
    int yoff[WS];
    bool ry[WS];
#pragma unroll
    for (int r = 0; r < WS; ++r) {
        int y = y0 + r;
        ry[r] = (unsigned)y < (unsigned)HIN;
        int yc = iclamp(y, 0, HIN - 1);
        yoff[r] = yc * HIN * CW;
    }
    int acc[HP * NA];
#pragma unroll
    for (int i = 0; i < HP * NA; ++i) acc[i] = 0;

    if (yp > 0 && yp < HP - 1)
        row_accum<CW, HIN, POOL, WC, true>(inb, wpkT, Co, co, yoff, ry, acc);
    else
        row_accum<CW, HIN, POOL, WC, false>(inb, wpkT, Co, co, yoff, ry, acc);

    int s1 = 0;
    long long s2 = 0;
    short* orow = out + (size_t)grow * HP * Co + co;
#pragma unroll
    for (int xp = 0; xp < HP; ++xp) {
        int ival;
        if constexpr (POOL)
            ival = imax(imax(acc[xp * 4], acc[xp * 4 + 1]), imax(acc[xp * 4 + 2], acc[xp * 4 + 3]));
        else
            ival = acc[xp];
        orow[(size_t)xp * Co] = (short)ival;
        s1 += ival;
        s2 += (long long)ival * ival;
    }

    __shared__ u64 sacc[128];
    if (threadIdx.x < 128) sacc[threadIdx.x] = 0ULL;
    __syncthreads();
    atomicAdd(&sacc[lane], (u64)(long long)s1);
    atomicAdd(&sacc[64 + lane], (u64)s2);
    __syncthreads();
    u64* sh = iacc + (size_t)(blockIdx.x & 7) * 1024;
    if (threadIdx.x < 64)
        atomicAdd(&sh[2 * (blockIdx.y * 64 + threadIdx.x)], sacc[threadIdx.x]);
    else if (threadIdx.x < 128)
        atomicAdd(&sh[2 * (blockIdx.y * 64 + threadIdx.x - 64) + 1], sacc[threadIdx.x]);
}

// ================= binary conv for tiny images (layers 5..7, HIN in {2,4}) =================
template <int CW, int HIN, bool POOL>
__global__ __launch_bounds__(256) void bconv_tiny(const u64* __restrict__ in,
                                                  const u64* __restrict__ wpkT,
                                                  short* __restrict__ out,
                                                  u64* __restrict__ iacc, int Co) {
    constexpr int NPX = HIN * HIN;
    constexpr int HP = POOL ? HIN / 2 : HIN;
    const int lane = threadIdx.x & 63;
    const int co = blockIdx.y * 64 + lane;
    const int n = blockIdx.x * 4 + (threadIdx.x >> 6);
    const u64* inb = in + (size_t)n * CW * NPX;
    int acc[NPX];
#pragma unroll
    for (int i = 0; i < NPX; ++i) acc[i] = 0;

#pragma unroll 1
    for (int w = 0; w < CW; ++w) {
        u64 win[NPX];
#pragma unroll
        for (int i = 0; i < NPX; ++i) win[i] = inb[i * CW + w];
#pragma unroll
        for (int k = 0; k < 9; ++k) {
            u64 wb = wpkT[(size_t)(k * CW + w) * Co + co];
            const int ky = k / 3, kx = k % 3;
#pragma unroll
            for (int py = 0; py < HIN; ++py)
#pragma unroll
                for (int px = 0; px < HIN; ++px) {
                    const int yy = py + ky - 1, xx = px + kx - 1;
                    if (yy >= 0 && yy < HIN && xx >= 0 && xx < HIN)
                        acc[py * HIN + px] += 64 - 2 * (int)__popcll(win[yy * HIN + xx] ^ wb);
                }
        }
    }

    short vals[HP * HP];
    if constexpr (POOL) {
#pragma unroll
        for (int py = 0; py < HP; ++py)
#pragma unroll
            for (int px = 0; px < HP; ++px)
                vals[py * HP + px] = (short)imax(
                    imax(acc[(2 * py) * HIN + 2 * px], acc[(2 * py) * HIN + 2 * px + 1]),
                    imax(acc[(2 * py + 1) * HIN + 2 * px], acc[(2 * py + 1) * HIN + 2 * px + 1]));
    } else {
#pragma unroll
        for (int i = 0; i < NPX; ++i) vals[i] = (short)acc[i];
    }
#pragma unroll
    for (int p = 0; p < HP * HP; ++p) out[(size_t)(n * HP * HP + p) * Co + co] = vals[p];

    long long s1 = 0, s2 = 0;
#pragma unroll
    for (int p = 0; p < HP * HP; ++p) {
        s1 += vals[p];
        s2 += (long long)vals[p] * vals[p];
    }
    __shared__ u64 sacc[128];
    if (threadIdx.x < 128) sacc[threadIdx.x] = 0ULL;
    __syncthreads();
    atomicAdd(&sacc[lane], (u64)s1);
    atomicAdd(&sacc[64 + lane], (u64)s2);
    __syncthreads();
    u64* sh = iacc + (size_t)(blockIdx.x & 7) * 1024;
    if (threadIdx.x < 64)
        atomicAdd(&sh[2 * (blockIdx.y * 64 + threadIdx.x)], sacc[threadIdx.x]);
    else if (threadIdx.x < 128)
        atomicAdd(&sh[2 * (blockIdx.y * 64 + threadIdx.x - 64) + 1], sacc[threadIdx.x]);
}

// ================= binarized linear + BN1 (+ hardtanh) =================
__global__ __launch_bounds__(256) void lin_kernel(const u64* __restrict__ hp,
                                                  const u64* __restrict__ wp,
                                                  const float* __restrict__ lb,
                                                  const float* __restrict__ g,
                                                  const float* __restrict__ bta,
                                                  float* __restrict__ z, int O, int applyHt) {
    int o = blockIdx.x;
    int n = threadIdx.x;
    const u64* hr = hp + n * 8;
    const u64* wr = wp + o * 8;
    int s = 0;
#pragma unroll
    for (int w = 0; w < 8; ++w) s += (int)__popcll(hr[w] ^ wr[w]);
    float val = (float)(512 - 2 * s) + lb[o];
    __shared__ double sh1[256], sh2[256];
    sh1[n] = (double)val;
    sh2[n] = (double)val * (double)val;
    __syncthreads();
    for (int st = 128; st > 0; st >>= 1) {
        if (n < st) {
            sh1[n] += sh1[n + st];
            sh2[n] += sh2[n + st];
        }
        __syncthreads();
    }
    __shared__ float sm, siv;
    if (n == 0) {
        double m = sh1[0] / 256.0;
        double var = sh2[0] / 256.0 - m * m;
        sm = (float)m;
        siv = (float)(1.0 / sqrt(var + EPSV));
    }
    __syncthreads();
    float zz = g[o] * (val - sm) * siv + bta[o];
    if (applyHt) zz = fminf(1.f, fmaxf(-1.f, zz));
    z[(size_t)n * O + o] = zz;
}

__global__ void pack_rows(const float* __restrict__ z, u64* __restrict__ hp) {
    int idx = blockIdx.x * 256 + threadIdx.x;
    if (idx >= 2048) return;
    int ww = idx & 7;
    int n = idx >> 3;
    u64 bits = 0;
    const float* row = z + (size_t)n * 512 + (ww << 6);
    for (int j = 0; j < 64; ++j) bits |= (u64)(row[j] >= 0.f) << j;
    hp[idx] = bits;
}

__global__ void lsm_kernel(const float* __restrict__ z, float* __restrict__ out) {
    int n = blockIdx.x * 64 + threadIdx.x;
    if (n >= 256) return;
    float v[10];
    float m = -1e30f;
#pragma unroll
    for (int i = 0; i < 10; ++i) {
        v[i] = z[n * 10 + i];
        m = fmaxf(m, v[i]);
    }
    float s = 0.f;
#pragma unroll
    for (int i = 0; i < 10; ++i) s += expf(v[i] - m);
    float ls = logf(s);
#pragma unroll
    for (int i = 0; i < 10; ++i) out[n * 10 + i] = v[i] - m - ls;
}

extern "C" void kernel_launch(void* const* d_in, const int* in_sizes, int n_in, void* d_out,
                              int out_size, void* d_ws, size_t ws_size, hipStream_t stream) {
    (void)in_sizes; (void)n_in; (void)out_size; (void)ws_size;
    const float* x = (const float*)d_in[0];
    const float *cw[8], *cb[8], *cg[8], *ct[8];
    for (int i = 0; i < 8; ++i) {
        cw[i] = (const float*)d_in[1 + 4 * i];
        cb[i] = (const float*)d_in[2 + 4 * i];
        cg[i] = (const float*)d_in[3 + 4 * i];
        ct[i] = (const float*)d_in[4 + 4 * i];
    }
    const float *lw[3], *lb[3], *lg[3], *lt[3];
    for (int i = 0; i < 3; ++i) {
        lw[i] = (const float*)d_in[33 + 4 * i];
        lb[i] = (const float*)d_in[34 + 4 * i];
        lg[i] = (const float*)d_in[35 + 4 * i];
        lt[i] = (const float*)d_in[36 + 4 * i];
    }

    static const int CIs[8] = {3, 64, 128, 256, 256, 512, 512, 512};
    static const int COs[8] = {64, 128, 256, 256, 512, 512, 512, 512};
    static const int HPs[8] = {16, 8, 8, 4, 4, 2, 2, 1};

    char* ws = (char*)d_ws;
    size_t off = 0;
    auto alloc = [&](size_t bytes) -> void* {
        void* p = ws + off;
        off += (bytes + 255) & ~(size_t)255;
        return p;
    };

    u64* wpkT[8] = {};
    for (int i = 1; i < 8; ++i) wpkT[i] = (u64*)alloc((size_t)COs[i] * 9 * (CIs[i] / 64) * 8);
    u64* wpl[3];
    int LO[3] = {512, 512, 10};
    for (int i = 0; i < 3; ++i) wpl[i] = (u64*)alloc((size_t)LO[i] * 8 * 8);
    u64* act[8];
    for (int i = 0; i < 8; ++i) act[i] = (u64*)alloc((size_t)256 * (COs[i] / 64) * HPs[i] * HPs[i] * 8);
    u64* fcs0 = (u64*)alloc(2048 * 8);
    u64* fcs1 = (u64*)alloc(2048 * 8);
    float* out0 = (float*)alloc((size_t)65536 * 64 * 4);
    short* i16A = (short*)alloc((size_t)16384 * 256 * 2);
    short* i16B = (short*)alloc((size_t)16384 * 256 * 2);
    float* z0 = (float*)alloc((size_t)256 * 512 * 4);
    float* z1 = (float*)alloc((size_t)256 * 512 * 4);
    float* z2 = (float*)alloc((size_t)256 * 10 * 4);
    // sharded stats: 8 layers x 8 shards x 1024 u64 (layer0 = doubles)
    u64* accs = (u64*)alloc((size_t)8 * 8 * 1024 * 8);
    double* dacc0 = (double*)accs;
    auto iacc = [&](int layer) { return accs + (size_t)layer * 8192; };

    // ---- prep ----
    PrepArgs pa;
    int rb = 0;
    for (int i = 1; i < 8; ++i) {
        int e = i - 1;
        pa.src[e] = cw[i];
        pa.dst[e] = wpkT[i];
        pa.CW[e] = CIs[i] / 64;
        pa.Co[e] = COs[i];
        pa.taps[e] = 9;
        pa.rowbase[e] = rb;
        rb += COs[i];
    }
    for (int i = 0; i < 3; ++i) {
        int e = 7 + i;
        pa.src[e] = lw[i];
        pa.dst[e] = wpl[i];
        pa.CW[e] = 8;
        pa.Co[e] = LO[i];
        pa.taps[e] = 1;
        pa.rowbase[e] = rb;
        rb += LO[i];
    }
    pa.rowbase[10] = rb;  // 3722
    pa.accs = accs;
    pa.naccs = 8 * 8 * 1024;
    prep_kernel<<<rb, 256, 0, stream>>>(pa);

    // ---- L0 ----
    conv0_lane<<<2048, 256, 0, stream>>>(x, cw[0], out0, dacc0);
    bnpack_f<<<256, 256, 0, stream>>>(out0, dacc0, cg[0], ct[0], act[0], 65536);

    // ---- L1: 64ch 16x16 -> 128ch, pool -> 8x8 (rows: 256*8=2048) ----
    bconv_row<1, 16, true, 1><<<dim3(512, 2), 256, 0, stream>>>(act[0], wpkT[1], i16A, iacc(1), 128);
    bnpack_i<<<128, 256, 0, stream>>>(i16A, iacc(1), cg[1], ct[1], act[1], 128, 1, 16384);

    // ---- L2: 128ch 8x8 -> 256ch (rows: 256*8=2048) ----
    bconv_row<2, 8, false, 2><<<dim3(512, 4), 256, 0, stream>>>(act[1], wpkT[2], i16B, iacc(2), 256);
    bnpack_i<<<256, 256, 0, stream>>>(i16B, iacc(2), cg[2], ct[2], act[2], 256, 2, 16384);

    // ---- L3: 256ch 8x8 -> 256ch, pool -> 4x4 (rows: 256*4=1024) ----
    bconv_row<4, 8, true, 2><<<dim3(256, 4), 256, 0, stream>>>(act[2], wpkT[3], i16A, iacc(3), 256);
    bnpack_i<<<64, 256, 0, stream>>>(i16A, iacc(3), cg[3], ct[3], act[3], 256, 2, 4096);

    // ---- L4: 256ch 4x4 -> 512ch (rows: 256*4=1024) ----
    bconv_row<4, 4, false, 2><<<dim3(256, 8), 256, 0, stream>>>(act[3], wpkT[4], i16B, iacc(4), 512);
    bnpack_i<<<128, 256, 0, stream>>>(i16B, iacc(4), cg[4], ct[4], act[4], 512, 3, 4096);

    // ---- L5: 512ch 4x4 -> 512ch, pool -> 2x2 (tiny) ----
    bconv_tiny<8, 4, true><<<dim3(64, 8), 256, 0, stream>>>(act[4], wpkT[5], i16A, iacc(5), 512);
    bnpack_i<<<32, 256, 0, stream>>>(i16A, iacc(5), cg[5], ct[5], act[5], 512, 3, 1024);

    // ---- L6: 512ch 2x2 -> 512ch (tiny) ----
    bconv_tiny<8, 2, false><<<dim3(64, 8), 256, 0, stream>>>(act[5], wpkT[6], i16B, iacc(6), 512);
    bnpack_i<<<32, 256, 0, stream>>>(i16B, iacc(6), cg[6], ct[6], act[6], 512, 3, 1024);

    // ---- L7: 512ch 2x2 -> 512ch, pool -> 1x1 (tiny) ----
    bconv_tiny<8, 2, true><<<dim3(64, 8), 256, 0, stream>>>(act[6], wpkT[7], i16A, iacc(7), 512);
    bnpack_i<<<8, 256, 0, stream>>>(i16A, iacc(7), cg[7], ct[7], act[7], 512, 3, 256);

    // ---- FC ----
    lin_kernel<<<512, 256, 0, stream>>>(act[7], wpl[0], lb[0], lg[0], lt[0], z0, 512, 1);
    pack_rows<<<8, 256, 0, stream>>>(z0, fcs0);
    lin_kernel<<<512, 256, 0, stream>>>(fcs0, wpl[1], lb[1], lg[1], lt[1], z1, 512, 1);
    pack_rows<<<8, 256, 0, stream>>>(z1, fcs1);
    lin_kernel<<<10, 256, 0, stream>>>(fcs1, wpl[2], lb[2], lg[2], lt[2], z2, 10, 0);
    lsm_kernel<<<4, 64, 0, stream>>>(z2, (float*)d_out);
}

// Round 10
// 385.791 us; speedup vs baseline: 1.4977x; 1.0472x over previous
//
#include <hip/hip_runtime.h>
#include <hip/hip_bf16.h>

typedef unsigned long long u64;

#define EPSV 1e-5

__device__ __forceinline__ int imax(int a, int b) { return a > b ? a : b; }
__device__ __forceinline__ int iclamp(int v, int lo, int hi) { return v < lo ? lo : (v > hi ? hi : v); }

// ================= prep: pack binary weights (coalesced via LDS) + zero stats shards =================
struct PrepArgs {
    const float* src[10];  // conv1..7 (l=0..6), lin0..2 (l=7..9)
    u64* dst[10];          // conv: transposed [k*CW+w][Co]; lin: [o][8]
    int CW[10];
    int Co[10];
    int taps[10];          // 9 conv, 1 lin
    int rowbase[11];       // prefix over Co
    u64* accs;
    int naccs;
};

__global__ __launch_bounds__(256) void prep_kernel(PrepArgs a) {
    __shared__ float buf[4608];  // max Ci*9 = 512*9
    const int blk = blockIdx.x;
    int z = blk * 18 + threadIdx.x;
    if (threadIdx.x < 18 && z < a.naccs) a.accs[z] = 0ULL;

    int l = 0;
    while (l < 9 && blk >= a.rowbase[l + 1]) ++l;
    const int row = blk - a.rowbase[l];
    const int CW = a.CW[l];
    const int taps = a.taps[l];
    const int nf = CW * 64 * taps;
    const float* srow = a.src[l] + (size_t)row * nf;
    for (int i = threadIdx.x; i < nf; i += 256) buf[i] = srow[i];
    __syncthreads();
    const int t = threadIdx.x;
    if (t < taps * CW) {
        u64 bits = 0;
        if (taps == 9) {
            int k = t % 9, w = t / 9;
            for (int j = 0; j < 64; ++j) bits |= (u64)(buf[(w * 64 + j) * 9 + k] >= 0.f) << j;
            a.dst[l][(size_t)(k * CW + w) * a.Co[l] + row] = bits;
        } else {
            for (int j = 0; j < 64; ++j) bits |= (u64)(buf[t * 64 + j] >= 0.f) << j;
            a.dst[l][(size_t)row * CW + t] = bits;
        }
    }
}

// ================= conv0: lane=co, input band staged in LDS, fused sharded stats =================
__global__ __launch_bounds__(256) void conv0_lane(const float* __restrict__ x,
                                                  const float* __restrict__ wgt,
                                                  float* __restrict__ out,
                                                  double* __restrict__ dacc) {
    const int lane = threadIdx.x & 63;
    const int wave = threadIdx.x >> 6;
    float ws[27];
#pragma unroll
    for (int j = 0; j < 27; ++j) ws[j] = (wgt[lane * 27 + j] >= 0.f) ? 1.f : -1.f;

    const int gp0 = blockIdx.x * 32;
    const int n = gp0 >> 8;
    const int ypA = (gp0 >> 4) & 15;
    const int yb = 2 * ypA - 1;

    __shared__ float simg[3][6][34];
    const float* xb = x + (size_t)n * 3072;
    for (int t = threadIdx.x; t < 612; t += 256) {
        int ci = t / 204;
        int rem = t % 204;
        int r = rem / 34;
        int cc = rem % 34;
        int yy = yb + r;
        int xx = cc - 1;
        float v = 0.f;
        if ((unsigned)yy < 32u && (unsigned)xx < 32u) v = xb[(ci * 32 + yy) * 32 + xx];
        simg[ci][r][cc] = v;
    }
    __syncthreads();

    double s1 = 0.0, s2 = 0.0;
#pragma unroll 2
    for (int pi = 0; pi < 8; ++pi) {
        const int lp = wave * 8 + pi;
        const int gp = gp0 + lp;
        const int xp = lp & 15;
        const int rbase = 2 * (lp >> 4);
        const int cbase = 2 * xp;
        float win[3][4][4];
#pragma unroll
        for (int ci = 0; ci < 3; ++ci)
#pragma unroll
            for (int r = 0; r < 4; ++r)
#pragma unroll
                for (int c = 0; c < 4; ++c) win[ci][r][c] = simg[ci][rbase + r][cbase + c];
        float a00 = 0.f, a01 = 0.f, a10 = 0.f, a11 = 0.f;
#pragma unroll
        for (int ci = 0; ci < 3; ++ci)
#pragma unroll
            for (int ky = 0; ky < 3; ++ky)
#pragma unroll
                for (int kx = 0; kx < 3; ++kx) {
                    float wv = ws[ci * 9 + ky * 3 + kx];
                    a00 += win[ci][ky][kx] * wv;
                    a01 += win[ci][ky][kx + 1] * wv;
                    a10 += win[ci][ky + 1][kx] * wv;
                    a11 += win[ci][ky + 1][kx + 1] * wv;
                }
        float val = fmaxf(fmaxf(a00, a01), fmaxf(a10, a11));
        out[(size_t)gp * 64 + lane] = val;
        s1 += (double)val;
        s2 += (double)val * (double)val;
    }
    __shared__ double sh1[4][64], sh2[4][64];
    sh1[wave][lane] = s1;
    sh2[wave][lane] = s2;
    __syncthreads();
    if (threadIdx.x < 64) {
        double t1 = 0.0, t2 = 0.0;
#pragma unroll
        for (int r = 0; r < 4; ++r) { t1 += sh1[r][threadIdx.x]; t2 += sh2[r][threadIdx.x]; }
        double* sh = dacc + (size_t)(blockIdx.x & 7) * 1024;
        atomicAdd(&sh[2 * threadIdx.x], t1);
        atomicAdd(&sh[2 * threadIdx.x + 1], t2);
    }
}

// ================= bnpack float (layer 0), 4-way word split, fused thresholds =================
// 4 threads per output word: each reads 16 floats (64 B), shuffle-OR combine.
__global__ __launch_bounds__(256) void bnpack_f(const float* __restrict__ in,
                                                const double* __restrict__ dacc,
                                                const float* __restrict__ g,
                                                const float* __restrict__ b,
                                                u64* __restrict__ act, int count) {
    __shared__ float2 sthr[64];
    if (threadIdx.x < 64) {
        int i = threadIdx.x;
        double S1 = 0.0, S2 = 0.0;
#pragma unroll
        for (int s = 0; s < 8; ++s) {
            S1 += dacc[s * 1024 + 2 * i];
            S2 += dacc[s * 1024 + 2 * i + 1];
        }
        double m = S1 / count;
        double var = S2 / count - m * m;
        double sc = (double)g[i] / sqrt(var + EPSV);
        float2 r;
        if (sc == 0.0) r = make_float2(b[i] >= 0.f ? -3.0e38f : 3.0e38f, 1.f);
        else {
            double t = m - (double)b[i] / sc;
            r = make_float2((float)t, sc > 0.0 ? 1.f : -1.f);
        }
        sthr[i] = r;
    }
    __syncthreads();
    int tid = blockIdx.x * 256 + threadIdx.x;
    int part = tid & 3;
    int word = tid >> 2;
    const float4* r4 = (const float4*)(in + (size_t)word * 64 + part * 16);
    u64 bits = 0;
#pragma unroll
    for (int q = 0; q < 4; ++q) {
        float4 v = r4[q];
        float vv[4] = {v.x, v.y, v.z, v.w};
#pragma unroll
        for (int u = 0; u < 4; ++u) {
            int c = part * 16 + q * 4 + u;
            float2 t = sthr[c];
            bool bit = (t.y > 0.f) ? (vv[u] >= t.x) : (vv[u] <= t.x);
            bits |= (u64)bit << c;
        }
    }
    bits |= __shfl_xor(bits, 1);
    bits |= __shfl_xor(bits, 2);
    if (part == 0) act[word] = bits;
}

// ================= bnpack int16, 4-way word split, padded threshold table =================
__global__ __launch_bounds__(256) void bnpack_i(const short* __restrict__ in,
                                                const u64* __restrict__ iacc,
                                                const float* __restrict__ g,
                                                const float* __restrict__ b,
                                                u64* __restrict__ act, int Co, int wshift,
                                                int count) {
    __shared__ int2 sthr[520];  // stride 65 breaks the 8-way bank conflict
    for (int i = threadIdx.x; i < Co; i += 256) {
        long long S1 = 0, S2 = 0;
#pragma unroll
        for (int s = 0; s < 8; ++s) {
            S1 += (long long)iacc[s * 1024 + 2 * i];
            S2 += (long long)iacc[s * 1024 + 2 * i + 1];
        }
        double m = (double)S1 / count;
        double var = (double)S2 / count - m * m;
        double sc = (double)g[i] / sqrt(var + EPSV);
        int2 r;
        if (sc == 0.0) r = make_int2(b[i] >= 0.f ? (int)0x80000000 : 0x7fffffff, 0);
        else {
            double t = m - (double)b[i] / sc;
            if (t > 1.0e9) t = 1.0e9;
            if (t < -1.0e9) t = -1.0e9;
            r = (sc > 0.0) ? make_int2((int)ceil(t), 0) : make_int2((int)floor(t), 1);
        }
        sthr[(i >> 6) * 65 + (i & 63)] = r;
    }
    __syncthreads();
    int tid = blockIdx.x * 256 + threadIdx.x;
    int part = tid & 3;
    int word = tid >> 2;
    int w = word & ((1 << wshift) - 1);
    int pix = word >> wshift;
    const int4* r4 = (const int4*)(in + (size_t)pix * Co + (w << 6) + part * 16);
    u64 bits = 0;
#pragma unroll
    for (int q = 0; q < 2; ++q) {
        int4 v = r4[q];
        int words4[4] = {v.x, v.y, v.z, v.w};
#pragma unroll
        for (int u = 0; u < 4; ++u) {
#pragma unroll
            for (int h = 0; h < 2; ++h) {
                int c = part * 16 + q * 8 + u * 2 + h;
                int val = (int)(short)((h == 0) ? (words4[u] & 0xffff) : ((unsigned)words4[u] >> 16));
                int2 t = sthr[w * 65 + c];
                bool bit = t.y ? (val <= t.x) : (val >= t.x);
                bits |= (u64)bit << c;
            }
        }
    }
    bits |= __shfl_xor(bits, 1);
    bits |= __shfl_xor(bits, 2);
    if (part == 0) act[word] = bits;
}

// ================= row-sliding binary conv, lane=co (layers 1..4) =================
// Wave = one output row (HP px); weights amortized over the row; sliding window
// registers. All array indices compile-time literals (dynamic index => scratch
// spill, round-4 disaster). INTERIOR: no per-tap selects (wave-uniform split).
template <int CW, int HIN, bool POOL, int WC, bool INTERIOR>
__device__ __forceinline__ void row_accum(const u64* __restrict__ inb,
                                          const u64* __restrict__ wpkT, int Co, int co,
                                          const int* yoff, const bool* ry, int* acc) {
    constexpr int HP = POOL ? HIN / 2 : HIN;
    constexpr int WS = POOL ? 4 : 3;
    constexpr int NA = POOL ? 4 : 1;
#pragma unroll 1
    for (int w0 = 0; w0 < CW; w0 += WC) {
        u64 wg[9 * WC];
#pragma unroll
        for (int k = 0; k < 9; ++k)
#pragma unroll
            for (int w = 0; w < WC; ++w)
                wg[k * WC + w] = wpkT[(size_t)(k * CW + w0 + w) * Co + co];
        u64 cur[WS][WS][WC];
#pragma unroll
        for (int d = 0; d < WS; ++d) {
            int cc = d - 1;
            int ccc = cc < 0 ? 0 : cc;
#pragma unroll
            for (int r = 0; r < WS; ++r) {
                const u64* p = inb + yoff[r] + ccc * CW + w0;
                if (WC == 1) {
                    cur[r][d][0] = p[0];
                } else {
                    ulonglong2 v = *(const ulonglong2*)p;
                    cur[r][d][0] = v.x;
                    cur[r][d][1] = v.y;
                }
            }
        }
#pragma unroll
        for (int xp = 0; xp < HP; ++xp) {
            if constexpr (POOL) {
#pragma unroll
                for (int py = 0; py < 2; ++py)
#pragma unroll
                    for (int qx = 0; qx < 2; ++qx)
#pragma unroll
                        for (int ky = 0; ky < 3; ++ky)
#pragma unroll
                            for (int kx = 0; kx < 3; ++kx) {
                                int d = qx + kx;
                                int cc = 2 * xp + d - 1;
                                if (cc >= 0 && cc < HIN) {  // folds (xp,d literal)
#pragma unroll
                                    for (int w = 0; w < WC; ++w) {
                                        int pcv = 64 - 2 * (int)__popcll(cur[py + ky][d][w] ^
                                                                         wg[(ky * 3 + kx) * WC + w]);
                                        if constexpr (INTERIOR)
                                            acc[xp * NA + py * 2 + qx] += pcv;
                                        else
                                            acc[xp * NA + py * 2 + qx] += ry[py + ky] ? pcv : 0;
                                    }
                                }
                            }
            } else {
#pragma unroll
                for (int ky = 0; ky < 3; ++ky)
#pragma unroll
                    for (int kx = 0; kx < 3; ++kx) {
                        int cc = xp + kx - 1;
                        if (cc >= 0 && cc < HIN) {
#pragma unroll
                            for (int w = 0; w < WC; ++w) {
                                int pcv = 64 - 2 * (int)__popcll(cur[ky][kx][w] ^
                                                                 wg[(ky * 3 + kx) * WC + w]);
                                if constexpr (INTERIOR)
                                    acc[xp] += pcv;
                                else
                                    acc[xp] += ry[ky] ? pcv : 0;
                            }
                        }
                    }
            }
            if (xp < HP - 1) {
                if constexpr (POOL) {
#pragma unroll
                    for (int r = 0; r < WS; ++r)
#pragma unroll
                        for (int w = 0; w < WC; ++w) {
                            cur[r][0][w] = cur[r][2][w];
                            cur[r][1][w] = cur[r][3][w];
                        }
#pragma unroll
                    for (int dd = 2; dd < 4; ++dd) {
                        int cc = 2 * (xp + 1) + dd - 1;
                        int ccc = cc >= HIN ? HIN - 1 : cc;
#pragma unroll
                        for (int r = 0; r < WS; ++r) {
                            const u64* p = inb + yoff[r] + ccc * CW + w0;
                            if (WC == 1) {
                                cur[r][dd][0] = p[0];
                            } else {
                                ulonglong2 v = *(const ulonglong2*)p;
                                cur[r][dd][0] = v.x;
                                cur[r][dd][1] = v.y;
                            }
                        }
                    }
                } else {
#pragma unroll
                    for (int r = 0; r < WS; ++r)
#pragma unroll
                        for (int w = 0; w < WC; ++w) {
                            cur[r][0][w] = cur[r][1][w];
                            cur[r][1][w] = cur[r][2][w];
                        }
                    int cc = xp + 2;
                    int ccc = cc >= HIN ? HIN - 1 : cc;
#pragma unroll
                    for (int r = 0; r < WS; ++r) {
                        const u64* p = inb + yoff[r] + ccc * CW + w0;
                        if (WC == 1) {
                            cur[r][2][0] = p[0];
                        } else {
                            ulonglong2 v = *(const ulonglong2*)p;
                            cur[r][2][0] = v.x;
                            cur[r][2][1] = v.y;
                        }
                    }
                }
            }
        }
    }
}

template <int CW, int HIN, bool POOL, int WC>
__global__ __launch_bounds__(256) void bconv_row(const u64* __restrict__ in,
                                                 const u64* __restrict__ wpkT,
                                                 short* __restrict__ out,
                                                 u64* __restrict__ iacc, int Co) {
    constexpr int HP = POOL ? HIN / 2 : HIN;
    constexpr int WS = POOL ? 4 : 3;
    constexpr int NA = POOL ? 4 : 1;
    const int lane = threadIdx.x & 63;
    const int co = blockIdx.y * 64 + lane;
    const int grow = blockIdx.x * 4 + (threadIdx.x >> 6);  // n*HP + yp
    const int n = grow / HP;
    const int yp = grow % HP;
    const int y0 = (POOL ? 2 * yp : yp) - 1;
    const u64* inb = in + (size_t)n * (HIN * HIN * CW);
    int yoff[WS];
    bool ry[WS];
#pragma unroll
    for (int r = 0; r < WS; ++r) {
        int y = y0 + r;
        ry[r] = (unsigned)y < (unsigned)HIN;
        int yc = iclamp(y, 0, HIN - 1);
        yoff[r] = yc * HIN * CW;
    }
    int acc[HP * NA];
#pragma unroll
    for (int i = 0; i < HP * NA; ++i) acc[i] = 0;

    if (yp > 0 && yp < HP - 1)
        row_accum<CW, HIN, POOL, WC, true>(inb, wpkT, Co, co, yoff, ry, acc);
    else
        row_accum<CW, HIN, POOL, WC, false>(inb, wpkT, Co, co, yoff, ry, acc);

    int s1 = 0;
    long long s2 = 0;
    short* orow = out + (size_t)grow * HP * Co + co;
#pragma unroll
    for (int xp = 0; xp < HP; ++xp) {
        int ival;
        if constexpr (POOL)
            ival = imax(imax(acc[xp * 4], acc[xp * 4 + 1]), imax(acc[xp * 4 + 2], acc[xp * 4 + 3]));
        else
            ival = acc[xp];
        orow[(size_t)xp * Co] = (short)ival;
        s1 += ival;
        s2 += (long long)ival * ival;
    }

    __shared__ u64 sacc[128];
    if (threadIdx.x < 128) sacc[threadIdx.x] = 0ULL;
    __syncthreads();
    atomicAdd(&sacc[lane], (u64)(long long)s1);
    atomicAdd(&sacc[64 + lane], (u64)s2);
    __syncthreads();
    u64* sh = iacc + (size_t)(blockIdx.x & 7) * 1024;
    if (threadIdx.x < 64)
        atomicAdd(&sh[2 * (blockIdx.y * 64 + threadIdx.x)], sacc[threadIdx.x]);
    else if (threadIdx.x < 128)
        atomicAdd(&sh[2 * (blockIdx.y * 64 + threadIdx.x - 64) + 1], sacc[threadIdx.x]);
}

// ================= binary conv for tiny images (layers 5..7, HIN in {2,4}) =================
template <int CW, int HIN, bool POOL>
__global__ __launch_bounds__(256) void bconv_tiny(const u64* __restrict__ in,
                                                  const u64* __restrict__ wpkT,
                                                  short* __restrict__ out,
                                                  u64* __restrict__ iacc, int Co) {
    constexpr int NPX = HIN * HIN;
    constexpr int HP = POOL ? HIN / 2 : HIN;
    const int lane = threadIdx.x & 63;
    const int co = blockIdx.y * 64 + lane;
    const int n = blockIdx.x * 4 + (threadIdx.x >> 6);
    const u64* inb = in + (size_t)n * CW * NPX;
    int acc[NPX];
#pragma unroll
    for (int i = 0; i < NPX; ++i) acc[i] = 0;

#pragma unroll 2
    for (int w = 0; w < CW; ++w) {
        u64 win[NPX];
#pragma unroll
        for (int i = 0; i < NPX; ++i) win[i] = inb[i * CW + w];
#pragma unroll
        for (int k = 0; k < 9; ++k) {
            u64 wb = wpkT[(size_t)(k * CW + w) * Co + co];
            const int ky = k / 3, kx = k % 3;
#pragma unroll
            for (int py = 0; py < HIN; ++py)
#pragma unroll
                for (int px = 0; px < HIN; ++px) {
                    const int yy = py + ky - 1, xx = px + kx - 1;
                    if (yy >= 0 && yy < HIN && xx >= 0 && xx < HIN)
                        acc[py * HIN + px] += 64 - 2 * (int)__popcll(win[yy * HIN + xx] ^ wb);
                }
        }
    }

    short vals[HP * HP];
    if constexpr (POOL) {
#pragma unroll
        for (int py = 0; py < HP; ++py)
#pragma unroll
            for (int px = 0; px < HP; ++px)
                vals[py * HP + px] = (short)imax(
                    imax(acc[(2 * py) * HIN + 2 * px], acc[(2 * py) * HIN + 2 * px + 1]),
                    imax(acc[(2 * py + 1) * HIN + 2 * px], acc[(2 * py + 1) * HIN + 2 * px + 1]));
    } else {
#pragma unroll
        for (int i = 0; i < NPX; ++i) vals[i] = (short)acc[i];
    }
#pragma unroll
    for (int p = 0; p < HP * HP; ++p) out[(size_t)(n * HP * HP + p) * Co + co] = vals[p];

    long long s1 = 0, s2 = 0;
#pragma unroll
    for (int p = 0; p < HP * HP; ++p) {
        s1 += vals[p];
        s2 += (long long)vals[p] * vals[p];
    }
    __shared__ u64 sacc[128];
    if (threadIdx.x < 128) sacc[threadIdx.x] = 0ULL;
    __syncthreads();
    atomicAdd(&sacc[lane], (u64)s1);
    atomicAdd(&sacc[64 + lane], (u64)s2);
    __syncthreads();
    u64* sh = iacc + (size_t)(blockIdx.x & 7) * 1024;
    if (threadIdx.x < 64)
        atomicAdd(&sh[2 * (blockIdx.y * 64 + threadIdx.x)], sacc[threadIdx.x]);
    else if (threadIdx.x < 128)
        atomicAdd(&sh[2 * (blockIdx.y * 64 + threadIdx.x - 64) + 1], sacc[threadIdx.x]);
}

// ================= binarized linear + BN1 (+ hardtanh) =================
__global__ __launch_bounds__(256) void lin_kernel(const u64* __restrict__ hp,
                                                  const u64* __restrict__ wp,
                                                  const float* __restrict__ lb,
                                                  const float* __restrict__ g,
                                                  const float* __restrict__ bta,
                                                  float* __restrict__ z, int O, int applyHt) {
    int o = blockIdx.x;
    int n = threadIdx.x;
    const u64* hr = hp + n * 8;
    const u64* wr = wp + o * 8;
    int s = 0;
#pragma unroll
    for (int w = 0; w < 8; ++w) s += (int)__popcll(hr[w] ^ wr[w]);
    float val = (float)(512 - 2 * s) + lb[o];
    __shared__ double sh1[256], sh2[256];
    sh1[n] = (double)val;
    sh2[n] = (double)val * (double)val;
    __syncthreads();
    for (int st = 128; st > 0; st >>= 1) {
        if (n < st) {
            sh1[n] += sh1[n + st];
            sh2[n] += sh2[n + st];
        }
        __syncthreads();
    }
    __shared__ float sm, siv;
    if (n == 0) {
        double m = sh1[0] / 256.0;
        double var = sh2[0] / 256.0 - m * m;
        sm = (float)m;
        siv = (float)(1.0 / sqrt(var + EPSV));
    }
    __syncthreads();
    float zz = g[o] * (val - sm) * siv + bta[o];
    if (applyHt) zz = fminf(1.f, fmaxf(-1.f, zz));
    z[(size_t)n * O + o] = zz;
}

// pack post-ht FC activations [256,512] -> [256,8], 4-way word split
__global__ void pack_rows(const float* __restrict__ z, u64* __restrict__ hp) {
    int tid = blockIdx.x * 256 + threadIdx.x;  // 8192 total
    int part = tid & 3;
    int word = tid >> 2;
    int ww = word & 7;
    int n = word >> 3;
    const float4* r4 = (const float4*)(z + (size_t)n * 512 + (ww << 6) + part * 16);
    u64 bits = 0;
#pragma unroll
    for (int q = 0; q < 4; ++q) {
        float4 v = r4[q];
        float vv[4] = {v.x, v.y, v.z, v.w};
#pragma unroll
        for (int u = 0; u < 4; ++u) bits |= (u64)(vv[u] >= 0.f) << (part * 16 + q * 4 + u);
    }
    bits |= __shfl_xor(bits, 1);
    bits |= __shfl_xor(bits, 2);
    if (part == 0) hp[word] = bits;
}

__global__ void lsm_kernel(const float* __restrict__ z, float* __restrict__ out) {
    int n = blockIdx.x * 64 + threadIdx.x;
    if (n >= 256) return;
    float v[10];
    float m = -1e30f;
#pragma unroll
    for (int i = 0; i < 10; ++i) {
        v[i] = z[n * 10 + i];
        m = fmaxf(m, v[i]);
    }
    float s = 0.f;
#pragma unroll
    for (int i = 0; i < 10; ++i) s += expf(v[i] - m);
    float ls = logf(s);
#pragma unroll
    for (int i = 0; i < 10; ++i) out[n * 10 + i] = v[i] - m - ls;
}

extern "C" void kernel_launch(void* const* d_in, const int* in_sizes, int n_in, void* d_out,
                              int out_size, void* d_ws, size_t ws_size, hipStream_t stream) {
    (void)in_sizes; (void)n_in; (void)out_size; (void)ws_size;
    const float* x = (const float*)d_in[0];
    const float *cw[8], *cb[8], *cg[8], *ct[8];
    for (int i = 0; i < 8; ++i) {
        cw[i] = (const float*)d_in[1 + 4 * i];
        cb[i] = (const float*)d_in[2 + 4 * i];
        cg[i] = (const float*)d_in[3 + 4 * i];
        ct[i] = (const float*)d_in[4 + 4 * i];
    }
    const float *lw[3], *lb[3], *lg[3], *lt[3];
    for (int i = 0; i < 3; ++i) {
        lw[i] = (const float*)d_in[33 + 4 * i];
        lb[i] = (const float*)d_in[34 + 4 * i];
        lg[i] = (const float*)d_in[35 + 4 * i];
        lt[i] = (const float*)d_in[36 + 4 * i];
    }

    static const int CIs[8] = {3, 64, 128, 256, 256, 512, 512, 512};
    static const int COs[8] = {64, 128, 256, 256, 512, 512, 512, 512};
    static const int HPs[8] = {16, 8, 8, 4, 4, 2, 2, 1};

    char* ws = (char*)d_ws;
    size_t off = 0;
    auto alloc = [&](size_t bytes) -> void* {
        void* p = ws + off;
        off += (bytes + 255) & ~(size_t)255;
        return p;
    };

    u64* wpkT[8] = {};
    for (int i = 1; i < 8; ++i) wpkT[i] = (u64*)alloc((size_t)COs[i] * 9 * (CIs[i] / 64) * 8);
    u64* wpl[3];
    int LO[3] = {512, 512, 10};
    for (int i = 0; i < 3; ++i) wpl[i] = (u64*)alloc((size_t)LO[i] * 8 * 8);
    u64* act[8];
    for (int i = 0; i < 8; ++i) act[i] = (u64*)alloc((size_t)256 * (COs[i] / 64) * HPs[i] * HPs[i] * 8);
    u64* fcs0 = (u64*)alloc(2048 * 8);
    u64* fcs1 = (u64*)alloc(2048 * 8);
    float* out0 = (float*)alloc((size_t)65536 * 64 * 4);
    short* i16A = (short*)alloc((size_t)16384 * 256 * 2);
    short* i16B = (short*)alloc((size_t)16384 * 256 * 2);
    float* z0 = (float*)alloc((size_t)256 * 512 * 4);
    float* z1 = (float*)alloc((size_t)256 * 512 * 4);
    float* z2 = (float*)alloc((size_t)256 * 10 * 4);
    // sharded stats: 8 layers x 8 shards x 1024 u64 (layer0 = doubles)
    u64* accs = (u64*)alloc((size_t)8 * 8 * 1024 * 8);
    double* dacc0 = (double*)accs;
    auto iacc = [&](int layer) { return accs + (size_t)layer * 8192; };

    // ---- prep ----
    PrepArgs pa;
    int rb = 0;
    for (int i = 1; i < 8; ++i) {
        int e = i - 1;
        pa.src[e] = cw[i];
        pa.dst[e] = wpkT[i];
        pa.CW[e] = CIs[i] / 64;
        pa.Co[e] = COs[i];
        pa.taps[e] = 9;
        pa.rowbase[e] = rb;
        rb += COs[i];
    }
    for (int i = 0; i < 3; ++i) {
        int e = 7 + i;
        pa.src[e] = lw[i];
        pa.dst[e] = wpl[i];
        pa.CW[e] = 8;
        pa.Co[e] = LO[i];
        pa.taps[e] = 1;
        pa.rowbase[e] = rb;
        rb += LO[i];
    }
    pa.rowbase[10] = rb;  // 3722
    pa.accs = accs;
    pa.naccs = 8 * 8 * 1024;
    prep_kernel<<<rb, 256, 0, stream>>>(pa);

    // ---- L0 ----
    conv0_lane<<<2048, 256, 0, stream>>>(x, cw[0], out0, dacc0);
    bnpack_f<<<1024, 256, 0, stream>>>(out0, dacc0, cg[0], ct[0], act[0], 65536);

    // ---- L1: 64ch 16x16 -> 128ch, pool -> 8x8 ----
    bconv_row<1, 16, true, 1><<<dim3(512, 2), 256, 0, stream>>>(act[0], wpkT[1], i16A, iacc(1), 128);
    bnpack_i<<<512, 256, 0, stream>>>(i16A, iacc(1), cg[1], ct[1], act[1], 128, 1, 16384);

    // ---- L2: 128ch 8x8 -> 256ch ----
    bconv_row<2, 8, false, 2><<<dim3(512, 4), 256, 0, stream>>>(act[1], wpkT[2], i16B, iacc(2), 256);
    bnpack_i<<<1024, 256, 0, stream>>>(i16B, iacc(2), cg[2], ct[2], act[2], 256, 2, 16384);

    // ---- L3: 256ch 8x8 -> 256ch, pool -> 4x4 ----
    bconv_row<4, 8, true, 2><<<dim3(256, 4), 256, 0, stream>>>(act[2], wpkT[3], i16A, iacc(3), 256);
    bnpack_i<<<256, 256, 0, stream>>>(i16A, iacc(3), cg[3], ct[3], act[3], 256, 2, 4096);

    // ---- L4: 256ch 4x4 -> 512ch ----
    bconv_row<4, 4, false, 2><<<dim3(256, 8), 256, 0, stream>>>(act[3], wpkT[4], i16B, iacc(4), 512);
    bnpack_i<<<512, 256, 0, stream>>>(i16B, iacc(4), cg[4], ct[4], act[4], 512, 3, 4096);

    // ---- L5: 512ch 4x4 -> 512ch, pool -> 2x2 (tiny) ----
    bconv_tiny<8, 4, true><<<dim3(64, 8), 256, 0, stream>>>(act[4], wpkT[5], i16A, iacc(5), 512);
    bnpack_i<<<128, 256, 0, stream>>>(i16A, iacc(5), cg[5], ct[5], act[5], 512, 3, 1024);

    // ---- L6: 512ch 2x2 -> 512ch (tiny) ----
    bconv_tiny<8, 2, false><<<dim3(64, 8), 256, 0, stream>>>(act[5], wpkT[6], i16B, iacc(6), 512);
    bnpack_i<<<128, 256, 0, stream>>>(i16B, iacc(6), cg[6], ct[6], act[6], 512, 3, 1024);

    // ---- L7: 512ch 2x2 -> 512ch, pool -> 1x1 (tiny) ----
    bconv_tiny<8, 2, true><<<dim3(64, 8), 256, 0, stream>>>(act[6], wpkT[7], i16A, iacc(7), 512);
    bnpack_i<<<32, 256, 0, stream>>>(i16A, iacc(7), cg[7], ct[7], act[7], 512, 3, 256);

    // ---- FC ----
    lin_kernel<<<512, 256, 0, stream>>>(act[7], wpl[0], lb[0], lg[0], lt[0], z0, 512, 1);
    pack_rows<<<32, 256, 0, stream>>>(z0, fcs0);
    lin_kernel<<<512, 256, 0, stream>>>(fcs0, wpl[1], lb[1], lg[1], lt[1], z1, 512, 1);
    pack_rows<<<32, 256, 0, stream>>>(z1, fcs1);
    lin_kernel<<<10, 256, 0, stream>>>(fcs1, wpl[2], lb[2], lg[2], lt[2], z2, 10, 0);
    lsm_kernel<<<4, 64, 0, stream>>>(z2, (float*)d_out);
}